// Round 1
// 1916.351 us; speedup vs baseline: 1.0483x; 1.0483x over previous
//
#include <hip/hip_runtime.h>

#define SEQ 4096
#define BATCH 8
#define HEADS 8
#define DMODEL 512
#define DK 64
#define PHI 128
#define CHUNK 1024
#define CROWS (CHUNK * BATCH)          // 8192 rows per chunk
#define SB 32                          // scan superblock (steps staged per barrier)
#define NSB (CHUNK / SB)               // 32

// ---------------- fp32 SGEMM: C[M,N] = A[M,K] @ B[K,N] (+bias) ----------------
// 128x128 tile, BK=16, 256 threads, 8x8 micro-tile.
template <bool BIAS>
__global__ __launch_bounds__(256)
void sgemm_kernel(const float* __restrict__ A, const float* __restrict__ B,
                  const float* __restrict__ bias, float* __restrict__ C,
                  int M, int N, int K)
{
    __shared__ __align__(16) float As[16][132];   // transposed A tile: As[k][m]
    __shared__ __align__(16) float Bs[16][128];   // Bs[k][n]
    const int t  = threadIdx.x;
    const int tx = t & 15;
    const int ty = t >> 4;
    const int bm = blockIdx.x * 128;
    const int bn = blockIdx.y * 128;

    float acc[8][8];
#pragma unroll
    for (int i = 0; i < 8; ++i)
#pragma unroll
        for (int j = 0; j < 8; ++j) acc[i][j] = 0.f;

    for (int k0 = 0; k0 < K; k0 += 16) {
#pragma unroll
        for (int i = 0; i < 2; ++i) {           // A tile: 128 rows x 16 k
            int lin = t + i * 256;
            int m   = lin >> 2;
            int kq  = (lin & 3) << 2;
            const float4 av = *(const float4*)(A + (size_t)(bm + m) * K + k0 + kq);
            As[kq + 0][m] = av.x; As[kq + 1][m] = av.y;
            As[kq + 2][m] = av.z; As[kq + 3][m] = av.w;
        }
#pragma unroll
        for (int i = 0; i < 2; ++i) {           // B tile: 16 k x 128 n
            int lin = t + i * 256;
            int kk  = lin >> 5;
            int n4  = (lin & 31) << 2;
            *(float4*)(&Bs[kk][n4]) = *(const float4*)(B + (size_t)(k0 + kk) * N + bn + n4);
        }
        __syncthreads();
#pragma unroll
        for (int k = 0; k < 16; ++k) {
            float af[8], bf[8];
            *(float4*)&af[0] = *(const float4*)&As[k][ty * 8];
            *(float4*)&af[4] = *(const float4*)&As[k][ty * 8 + 4];
            *(float4*)&bf[0] = *(const float4*)&Bs[k][tx * 4];
            *(float4*)&bf[4] = *(const float4*)&Bs[k][64 + tx * 4];
#pragma unroll
            for (int i = 0; i < 8; ++i)
#pragma unroll
                for (int j = 0; j < 8; ++j) acc[i][j] = fmaf(af[i], bf[j], acc[i][j]);
        }
        __syncthreads();
    }

#pragma unroll
    for (int i = 0; i < 8; ++i) {
        const int row = bm + ty * 8 + i;
        float4 o0, o1;
        o0.x = acc[i][0]; o0.y = acc[i][1]; o0.z = acc[i][2]; o0.w = acc[i][3];
        o1.x = acc[i][4]; o1.y = acc[i][5]; o1.z = acc[i][6]; o1.w = acc[i][7];
        if (BIAS) {
            const float4 b0 = *(const float4*)(bias + bn + tx * 4);
            const float4 b1 = *(const float4*)(bias + bn + 64 + tx * 4);
            o0.x += b0.x; o0.y += b0.y; o0.z += b0.z; o0.w += b0.w;
            o1.x += b1.x; o1.y += b1.y; o1.z += b1.z; o1.w += b1.w;
        }
        *(float4*)(C + (size_t)row * N + bn + tx * 4)      = o0;
        *(float4*)(C + (size_t)row * N + bn + 64 + tx * 4) = o1;
    }
}

// ---------------- dpfp: [CROWS*8, 64] -> [CROWS*8, 128], L1-normalized ----------------
__global__ __launch_bounds__(256)
void dpfp_kernel(const float* __restrict__ X, float* __restrict__ Y)
{
    const int gid  = blockIdx.x * 256 + threadIdx.x;
    const int wid  = gid >> 6;                 // row id
    const int lane = threadIdx.x & 63;
    const float xv = X[(size_t)wid * 64 + lane];
    const float ap = fmaxf(xv, 0.f);
    const float an = fmaxf(-xv, 0.f);
    const float a_prev = __shfl(ap, (lane + 63) & 63);   // lane-1 (lane0 -> lane63)
    const float b_prev = __shfl(an, (lane + 63) & 63);
    const float y0 = ap * ((lane == 0) ? b_prev : a_prev);
    const float y1 = an * ((lane == 0) ? a_prev : b_prev);
    float s = y0 + y1;
    s += __shfl_xor(s, 1);
    s += __shfl_xor(s, 2);
    s += __shfl_xor(s, 4);
    s += __shfl_xor(s, 8);
    s += __shfl_xor(s, 16);
    s += __shfl_xor(s, 32);
    const float inv = 1.f / (s + 1e-6f);
    Y[(size_t)wid * 128 + lane]      = y0 * inv;
    Y[(size_t)wid * 128 + 64 + lane] = y1 * inv;
}

// ---------------- gate: beta = sigmoid(x @ Wg), [32768, 8], whole sequence ----------------
__global__ __launch_bounds__(256)
void gemm_g_kernel(const float* __restrict__ X, const float* __restrict__ Wg,
                   float* __restrict__ Bt)
{
    const int idx = blockIdx.x * 256 + threadIdx.x;   // 262144 total
    const int row = idx >> 3;
    const int c   = idx & 7;
    const float4* x4 = (const float4*)(X + (size_t)row * DMODEL);
    float acc = 0.f;
    for (int k4 = 0; k4 < 128; ++k4) {
        const float4 xv = x4[k4];
        acc = fmaf(xv.x, Wg[(k4 * 4 + 0) * 8 + c], acc);
        acc = fmaf(xv.y, Wg[(k4 * 4 + 1) * 8 + c], acc);
        acc = fmaf(xv.z, Wg[(k4 * 4 + 2) * 8 + c], acc);
        acc = fmaf(xv.w, Wg[(k4 * 4 + 3) * 8 + c], acc);
    }
    Bt[idx] = 1.f / (1.f + expf(-acc));
}

// ---------------- scan ----------------
__device__ __forceinline__ float rowsum16(float x)
{
    x += __int_as_float(__builtin_amdgcn_update_dpp(0, __float_as_int(x), 0x121, 0xF, 0xF, true)); // row_ror:1
    x += __int_as_float(__builtin_amdgcn_update_dpp(0, __float_as_int(x), 0x122, 0xF, 0xF, true)); // row_ror:2
    x += __int_as_float(__builtin_amdgcn_update_dpp(0, __float_as_int(x), 0x124, 0xF, 0xF, true)); // row_ror:4
    x += __int_as_float(__builtin_amdgcn_update_dpp(0, __float_as_int(x), 0x128, 0xF, 0xF, true)); // row_ror:8
    return x;
}

__device__ __forceinline__ float dot8(const float4 x0, const float4 x1,
                                      const float4 y0, const float4 y1)
{
    float a = x0.x * y0.x;
    float b = x1.x * y1.x;
    a = fmaf(x0.y, y0.y, a); b = fmaf(x1.y, y1.y, b);
    a = fmaf(x0.z, y0.z, a); b = fmaf(x1.z, y1.z, b);
    a = fmaf(x0.w, y0.w, a); b = fmaf(x1.w, y1.w, b);
    return a + b;
}

__device__ __forceinline__ void async16(const float* g, float* l)
{
    __builtin_amdgcn_global_load_lds((const __attribute__((address_space(1))) void*)g,
                                     (__attribute__((address_space(3))) void*)l, 16, 0, 0);
}
__device__ __forceinline__ void async4(const float* g, float* l)
{
    __builtin_amdgcn_global_load_lds((const __attribute__((address_space(1))) void*)g,
                                     (__attribute__((address_space(3))) void*)l, 4, 0, 0);
}

// Row-independent delta-rule chains, one CHUNK of steps. Block = (b,h, row-group of 16).
// 256 threads = 16 rows x 16 col-lanes. Thread c owns cols [4c,4c+4) U [64+4c,64+4c+4).
//
// 2-STEP LOOK-AHEAD RECURRENCE (this round's change): the delta rule
//   a_s = w_{s-1}.k_s ; d_s = b_s (v_s - a_s) ; w_s = w_{s-1} + d_s k_s ; o_s = w_s.q_s
// is linearized with data-only scalars kk_s = k_{s-1}.k_s, kq1_s = k_{s-1}.q_s,
// kq0_s = k_s.q_s (shared across all 64 rows of a (b,h); computed cooperatively per
// superblock from the staged LDS tiles — no extra HBM traffic):
//   a_s = (w_{s-2}.k_s) + d_{s-1} kk_s
//   o_s = (w_{s-2}.q_s) + d_{s-1} kq1_s + d_s kq0_s
//   w   += d_{s-1} k_{s-1}        (state kept with a 2-step lag)
// so the per-step SERIAL chain is just two dependent FMAs (d_{s-1} -> a_s -> d_s);
// dots/reductions/updates get >=2 steps of slack and pipeline across the unroll.
// The previous version serialized ~21 dependent VALU ops per step, which at
// 1 wave/SIMD (grid-limited occupancy) exposed every latency cycle (452 cyc/step
// measured vs ~85 cyc issue floor, VALUBusy 44.7%).
__global__ __launch_bounds__(256)
void scan_kernel(const float* __restrict__ Qp, const float* __restrict__ Kp,
                 const float* __restrict__ Vd, const float* __restrict__ Bt,
                 float* __restrict__ outs, float* __restrict__ Wst,
                 int s0, int first)
{
    const int blk = blockIdx.x;
    const int bh  = blk & 63;
    const int rg  = blk >> 6;
    const int b   = bh >> 3;
    const int h   = bh & 7;
    const int t   = threadIdx.x;
    const int c      = t & 15;     // col lane
    const int rloc   = t >> 4;     // row within group of 16
    const int wv  = t >> 6;        // wave id 0..3
    const int ln  = t & 63;        // lane within wave

    __shared__ __align__(16) float sk[2][SB][PHI];
    __shared__ __align__(16) float sq[2][SB][PHI];
    __shared__ __align__(16) float sv[2][SB][16];
    __shared__ __align__(16) float sb2[2][SB];
    __shared__ __align__(16) float sd[2][SB][4];   // {kk, kq1, kq0, pad}

    const size_t bh128 = (size_t)(b * 8 + h) * 128;

    // w[0..3] = cols [4c,4c+4), w[4..7] = cols [64+4c,64+4c+4)
    float w[8];
    float* wslot = Wst + (size_t)blk * 2048 + t * 8;
    if (first) {
#pragma unroll
        for (int j = 0; j < 8; ++j) w[j] = 0.f;
    } else {
        const float4 w0 = *(const float4*)(wslot);
        const float4 w1 = *(const float4*)(wslot + 4);
        w[0] = w0.x; w[1] = w0.y; w[2] = w0.z; w[3] = w0.w;
        w[4] = w1.x; w[5] = w1.y; w[6] = w1.z; w[7] = w1.w;
    }

    // -------- staging: one superblock (32 steps) of K,Q,V,beta into LDS buffer sbuf ----
    auto stage = [&](int sbuf, int sb) {
        const int sqb = sb * SB;                 // first chunk-local step of superblock
        if (wv < 2) {
            // K: 1024 float4, waves 0,1 x 8 iters
#pragma unroll
            for (int i = 0; i < 8; ++i) {
                const int L  = i * 128 + wv * 64 + ln;   // 0..1023
                const int sl = L >> 5, c4 = L & 31;
                async16(Kp + (size_t)(sqb + sl) * 8192 + bh128 + c4 * 4,
                        &sk[sbuf][0][0] + L * 4);
            }
            // V: 128 float4, waves 0,1 x 1 iter
            {
                const int L  = wv * 64 + ln;             // 0..127
                const int sl = L >> 2, c4 = L & 3;
                async16(Vd + (size_t)(sqb + sl) * 4096 + b * 512 + h * 64 + rg * 16 + c4 * 4,
                        &sv[sbuf][0][0] + L * 4);
            }
        } else {
            // Q: 1024 float4, waves 2,3 x 8 iters
#pragma unroll
            for (int i = 0; i < 8; ++i) {
                const int L  = i * 128 + (wv - 2) * 64 + ln;
                const int sl = L >> 5, c4 = L & 31;
                async16(Qp + (size_t)(sqb + sl) * 8192 + bh128 + c4 * 4,
                        &sq[sbuf][0][0] + L * 4);
            }
            // beta: 32 floats, wave 2 lanes 0..31
            if (wv == 2 && ln < SB) {
                async4(Bt + (size_t)(s0 + sqb + ln) * 64 + b * 8 + h,
                       &sb2[sbuf][0] + ln);
            }
        }
    };

    // -------- cooperative per-superblock dot scalars: kk, kq1, kq0 for 32 steps -------
    // thread (c, rloc) handles steps sl0=2*rloc and sl0+1; for sl0 the "previous k"
    // comes from the OTHER buffer's last row (previous superblock, still intact — the
    // overwriting stage() is only issued after the second barrier). For the chunk's
    // very first step the value is multiplied by d_prev=0, but we store literal 0 to
    // avoid 0*NaN from stale LDS.
    auto dots_phase = [&](int buf, int sb) {
        const int sl0 = 2 * rloc;
        const float* kmp = (rloc == 0) ? &sk[buf ^ 1][SB - 1][0] : &sk[buf][sl0 - 1][0];
        const float4 km0 = *(const float4*)(kmp + 4 * c);
        const float4 km1 = *(const float4*)(kmp + 64 + 4 * c);
        const float4 ka0 = *(const float4*)&sk[buf][sl0][4 * c];
        const float4 ka1 = *(const float4*)&sk[buf][sl0][64 + 4 * c];
        const float4 kb0 = *(const float4*)&sk[buf][sl0 + 1][4 * c];
        const float4 kb1 = *(const float4*)&sk[buf][sl0 + 1][64 + 4 * c];
        const float4 qa0 = *(const float4*)&sq[buf][sl0][4 * c];
        const float4 qa1 = *(const float4*)&sq[buf][sl0][64 + 4 * c];
        const float4 qb0 = *(const float4*)&sq[buf][sl0 + 1][4 * c];
        const float4 qb1 = *(const float4*)&sq[buf][sl0 + 1][64 + 4 * c];
        const float kk_a  = rowsum16(dot8(km0, km1, ka0, ka1));
        const float kq1_a = rowsum16(dot8(km0, km1, qa0, qa1));
        const float kq0_a = rowsum16(dot8(ka0, ka1, qa0, qa1));
        const float kk_b  = rowsum16(dot8(ka0, ka1, kb0, kb1));
        const float kq1_b = rowsum16(dot8(ka0, ka1, qb0, qb1));
        const float kq0_b = rowsum16(dot8(kb0, kb1, qb0, qb1));
        if (c == 0) {
            const bool z = (sb == 0) && (rloc == 0);   // chunk's step 0: d_prev == 0
            sd[buf][sl0][0] = z ? 0.f : kk_a;
            sd[buf][sl0][1] = z ? 0.f : kq1_a;
            sd[buf][sl0][2] = kq0_a;
            sd[buf][sl0 + 1][0] = kk_b;
            sd[buf][sl0 + 1][1] = kq1_b;
            sd[buf][sl0 + 1][2] = kq0_b;
        }
    };

    struct Frag { float4 k0, k1, q0, q1; float bb, bv, kk, kq1, kq0; };
    Frag r[4];
    float d_prev = 0.f;

    auto preload = [&](Frag& f, int sbuf, int sl) {
        f.k0 = *(const float4*)&sk[sbuf][sl][4 * c];
        f.k1 = *(const float4*)&sk[sbuf][sl][64 + 4 * c];
        f.q0 = *(const float4*)&sq[sbuf][sl][4 * c];
        f.q1 = *(const float4*)&sq[sbuf][sl][64 + 4 * c];
        f.bb = sb2[sbuf][sl];
        f.bv = f.bb * sv[sbuf][sl][rloc];
        const float4 dd = *(const float4*)&sd[sbuf][sl][0];
        f.kk = dd.x; f.kq1 = dd.y; f.kq0 = dd.z;
    };

    // iteration g: entering w = w_{g-2}; f = frag g, fp = frag g-1
    auto step_compute = [&](const Frag& f, const Frag& fp, int g) {
        // dots against the lagged state (off the critical path; >=2 steps of slack)
        float A0 = w[0] * f.k0.x;
        float A1 = w[4] * f.k1.x;
        A0 = fmaf(w[1], f.k0.y, A0); A1 = fmaf(w[5], f.k1.y, A1);
        A0 = fmaf(w[2], f.k0.z, A0); A1 = fmaf(w[6], f.k1.z, A1);
        A0 = fmaf(w[3], f.k0.w, A0); A1 = fmaf(w[7], f.k1.w, A1);
        float Q0 = w[0] * f.q0.x;
        float Q1 = w[4] * f.q1.x;
        Q0 = fmaf(w[1], f.q0.y, Q0); Q1 = fmaf(w[5], f.q1.y, Q1);
        Q0 = fmaf(w[2], f.q0.z, Q0); Q1 = fmaf(w[6], f.q1.z, Q1);
        Q0 = fmaf(w[3], f.q0.w, Q0); Q1 = fmaf(w[7], f.q1.w, Q1);
        const float Ar  = rowsum16(A0 + A1);
        const float Aqr = rowsum16(Q0 + Q1);
        // lagged state update: w_{g-2} -> w_{g-1}
        w[0] = fmaf(d_prev, fp.k0.x, w[0]);
        w[1] = fmaf(d_prev, fp.k0.y, w[1]);
        w[2] = fmaf(d_prev, fp.k0.z, w[2]);
        w[3] = fmaf(d_prev, fp.k0.w, w[3]);
        w[4] = fmaf(d_prev, fp.k1.x, w[4]);
        w[5] = fmaf(d_prev, fp.k1.y, w[5]);
        w[6] = fmaf(d_prev, fp.k1.z, w[6]);
        w[7] = fmaf(d_prev, fp.k1.w, w[7]);
        // the only serial chain: d_{g-1} -> a_g -> d_g (2 FMAs)
        const float a = fmaf(d_prev, f.kk, Ar);
        const float d = fmaf(-f.bb, a, f.bv);
        // output (off critical path)
        float o = fmaf(d_prev, f.kq1, Aqr);
        o = fmaf(d, f.kq0, o);
        if (c == 0)
            outs[(size_t)(g * BATCH + b) * DMODEL + h * DK + rg * 16 + rloc] = o;
        d_prev = d;
    };

    // frag-(-1) k must be 0 (multiplied by d_prev=0; avoid NaN from stale regs)
    r[3].k0 = make_float4(0.f, 0.f, 0.f, 0.f);
    r[3].k1 = make_float4(0.f, 0.f, 0.f, 0.f);

    stage(0, 0);
    for (int sb = 0; sb < NSB; ++sb) {
        const int buf = sb & 1;
        __syncthreads();                     // staged loads for buf complete (vmcnt drain)
        dots_phase(buf, sb);
        __syncthreads();                     // sd visible; prev-buffer boundary reads done
        if (sb + 1 < NSB) stage(buf ^ 1, sb + 1);
        preload(r[0], buf, 0);               // (sb*SB)&3 == 0 since SB%4==0
        preload(r[1], buf, 1);
#pragma unroll
        for (int s = 0; s < SB; ++s) {
            if (s + 2 < SB) preload(r[(s + 2) & 3], buf, s + 2);  // slots 0,1 refilled post-barrier
            step_compute(r[s & 3], r[(s + 3) & 3], sb * SB + s);
        }
    }

    // apply the pending final update (d_{1023} * k_{1023}; frag 1023 lives in slot 3)
    w[0] = fmaf(d_prev, r[3].k0.x, w[0]);
    w[1] = fmaf(d_prev, r[3].k0.y, w[1]);
    w[2] = fmaf(d_prev, r[3].k0.z, w[2]);
    w[3] = fmaf(d_prev, r[3].k0.w, w[3]);
    w[4] = fmaf(d_prev, r[3].k1.x, w[4]);
    w[5] = fmaf(d_prev, r[3].k1.y, w[5]);
    w[6] = fmaf(d_prev, r[3].k1.z, w[6]);
    w[7] = fmaf(d_prev, r[3].k1.w, w[7]);

    // persist state for next chunk
    float4 w0, w1;
    w0.x = w[0]; w0.y = w[1]; w0.z = w[2]; w0.w = w[3];
    w1.x = w[4]; w1.y = w[5]; w1.z = w[6]; w1.w = w[7];
    *(float4*)(wslot)     = w0;
    *(float4*)(wslot + 4) = w1;
}

extern "C" void kernel_launch(void* const* d_in, const int* in_sizes, int n_in,
                              void* d_out, int out_size, void* d_ws, size_t ws_size,
                              hipStream_t stream)
{
    const float* x  = (const float*)d_in[0];
    const float* Wq = (const float*)d_in[1];
    const float* Wk = (const float*)d_in[2];
    const float* Wv = (const float*)d_in[3];
    const float* Wg = (const float*)d_in[4];
    const float* Wo = (const float*)d_in[5];
    const float* bo = (const float*)d_in[6];
    float* out = (float*)d_out;

    // workspace (floats), chunked to ~104 MB total:
    //   Qp[CROWS*1024] Kp[CROWS*1024] Vd[CROWS*512] tmp[CROWS*512] Bt[32768*8] Wst[256*2048]
    float* ws  = (float*)d_ws;
    float* Qp  = ws;
    float* Kp  = Qp + (size_t)CROWS * 1024;
    float* Vd  = Kp + (size_t)CROWS * 1024;
    float* tmp = Vd + (size_t)CROWS * 512;
    float* Bt  = tmp + (size_t)CROWS * 512;
    float* Wst = Bt + (size_t)(SEQ * BATCH) * 8;
    (void)in_sizes; (void)n_in; (void)out_size; (void)ws_size;

    const dim3 gg(CROWS / 128, 4);   // (64, 4) = 256 workgroups
    const int NCH = SEQ / CHUNK;     // 4

    gemm_g_kernel<<<(SEQ * BATCH * 8) / 256, 256, 0, stream>>>(x, Wg, Bt);

    for (int c = 0; c < NCH; ++c) {
        const float* xc = x + (size_t)c * CROWS * DMODEL;
        sgemm_kernel<false><<<gg, 256, 0, stream>>>(xc, Wq, nullptr, tmp, CROWS, DMODEL, DMODEL);
        dpfp_kernel<<<(CROWS * 8) / 4, 256, 0, stream>>>(tmp, Qp);
        sgemm_kernel<false><<<gg, 256, 0, stream>>>(xc, Wk, nullptr, tmp, CROWS, DMODEL, DMODEL);
        dpfp_kernel<<<(CROWS * 8) / 4, 256, 0, stream>>>(tmp, Kp);
        sgemm_kernel<false><<<gg, 256, 0, stream>>>(xc, Wv, nullptr, Vd, CROWS, DMODEL, DMODEL);
        scan_kernel<<<256, 256, 0, stream>>>(Qp, Kp, Vd, Bt, tmp, Wst,
                                             c * CHUNK, c == 0 ? 1 : 0);
        sgemm_kernel<true><<<gg, 256, 0, stream>>>(tmp, Wo, bo,
                                                   out + (size_t)c * CROWS * DMODEL,
                                                   CROWS, DMODEL, DMODEL);
    }
}

// Round 3
// 1771.222 us; speedup vs baseline: 1.1342x; 1.0819x over previous
//
#include <hip/hip_runtime.h>

#define SEQ 4096
#define BATCH 8
#define HEADS 8
#define DMODEL 512
#define DK 64
#define PHI 128
#define CHUNK 1024
#define CROWS (CHUNK * BATCH)          // 8192 rows per chunk
#define SB 32                          // scan superblock (steps staged per barrier)
#define NSB (CHUNK / SB)               // 32

__device__ __forceinline__ void async16(const float* g, float* l)
{
    __builtin_amdgcn_global_load_lds((const __attribute__((address_space(1))) void*)g,
                                     (__attribute__((address_space(3))) void*)l, 16, 0, 0);
}
__device__ __forceinline__ void async4(const float* g, float* l)
{
    __builtin_amdgcn_global_load_lds((const __attribute__((address_space(1))) void*)g,
                                     (__attribute__((address_space(3))) void*)l, 4, 0, 0);
}

__device__ __forceinline__ float rowsum16(float x)
{
    x += __int_as_float(__builtin_amdgcn_update_dpp(0, __float_as_int(x), 0x121, 0xF, 0xF, true)); // row_ror:1
    x += __int_as_float(__builtin_amdgcn_update_dpp(0, __float_as_int(x), 0x122, 0xF, 0xF, true)); // row_ror:2
    x += __int_as_float(__builtin_amdgcn_update_dpp(0, __float_as_int(x), 0x124, 0xF, 0xF, true)); // row_ror:4
    x += __int_as_float(__builtin_amdgcn_update_dpp(0, __float_as_int(x), 0x128, 0xF, 0xF, true)); // row_ror:8
    return x;
}

__device__ __forceinline__ float dot8(const float4 x0, const float4 x1,
                                      const float4 y0, const float4 y1)
{
    float a  = x0.x * y0.x;
    float b2 = x1.x * y1.x;
    a = fmaf(x0.y, y0.y, a); b2 = fmaf(x1.y, y1.y, b2);
    a = fmaf(x0.z, y0.z, a); b2 = fmaf(x1.z, y1.z, b2);
    a = fmaf(x0.w, y0.w, a); b2 = fmaf(x1.w, y1.w, b2);
    return a + b2;
}

// ---------------- transpose: X[8192][512] -> XT[512][8192], 64x64 tiles ----------------
__global__ __launch_bounds__(256)
void transpose_kernel(const float* __restrict__ X, float* __restrict__ XT)
{
    __shared__ float tile[64][65];
    const int t  = threadIdx.x;
    const int tx = t & 15;
    const int ty = t >> 4;
    const int bm = blockIdx.x * 64;   // row block in X
    const int bn = blockIdx.y * 64;   // col block in X
#pragma unroll
    for (int i = 0; i < 4; ++i) {
        const int r = ty + i * 16;
        const float4 v = *(const float4*)(X + (size_t)(bm + r) * 512 + bn + tx * 4);
        tile[r][tx * 4 + 0] = v.x; tile[r][tx * 4 + 1] = v.y;
        tile[r][tx * 4 + 2] = v.z; tile[r][tx * 4 + 3] = v.w;
    }
    __syncthreads();
#pragma unroll
    for (int i = 0; i < 4; ++i) {
        const int r = ty + i * 16;    // XT row = bn + r
        float4 v;
        v.x = tile[tx * 4 + 0][r];
        v.y = tile[tx * 4 + 1][r];
        v.z = tile[tx * 4 + 2][r];
        v.w = tile[tx * 4 + 3][r];
        *(float4*)(XT + (size_t)(bn + r) * CROWS + bm + tx * 4) = v;
    }
}

// ---------------- TN GEMM: C[M=8192][*] = AT[512][8192]^T @ B[512][512] ----------------
// Tile 128(M) x 64(N), BK=16, 256 threads, 8x4 micro-tile, double-buffered LDS with
// global_load_lds staging (one barrier per K-tile — scan-proven pattern).
// Grid (64, 8) = 512 blocks -> 2 blocks/CU -> 2 waves/SIMD (vs 1 before: the old
// sgemm sat at ~42% of the fp32 peak with 1 wave/SIMD + sync staging).
// MODE: 0 = plain store, 1 = +bias, 2 = fused dpfp (N-tile == one head; writes
// L1-normalized [*,128] features at C[m*ldc + h*128 + ...]).
template <int MODE>
__global__ __launch_bounds__(256)
void gemm_tn(const float* __restrict__ AT, const float* __restrict__ B,
             const float* __restrict__ bias, float* __restrict__ C,
             int ldat, int ldc)
{
    __shared__ __align__(16) float As[2][16][128];
    __shared__ __align__(16) float Bs[2][16][64];
    const int t  = threadIdx.x;
    const int tx = t & 15;
    const int ty = t >> 4;
    const int bm = blockIdx.x * 128;
    const int bn = blockIdx.y * 64;

    float acc[8][4];
#pragma unroll
    for (int i = 0; i < 8; ++i)
#pragma unroll
        for (int j = 0; j < 4; ++j) acc[i][j] = 0.f;

    auto stage = [&](int buf, int kt) {
        const int k0 = kt * 16;
        // A tile: 16 k-rows x 128 m = 512 float4 (wave-linear LDS dest)
#pragma unroll
        for (int i = 0; i < 2; ++i) {
            const int L = t + i * 256;
            const int k = L >> 5, c4 = L & 31;
            async16(AT + (size_t)(k0 + k) * ldat + bm + c4 * 4,
                    &As[buf][0][0] + L * 4);
        }
        // B tile: 16 k-rows x 64 n = 256 float4
        {
            const int k = t >> 4, c4 = t & 15;
            async16(B + (size_t)(k0 + k) * 512 + bn + c4 * 4,
                    &Bs[buf][0][0] + t * 4);
        }
    };

    stage(0, 0);
    for (int kt = 0; kt < 32; ++kt) {
        const int buf = kt & 1;
        __syncthreads();                 // vmcnt drain: buf's staged loads landed
        if (kt + 1 < 32) stage(buf ^ 1, kt + 1);
#pragma unroll
        for (int k = 0; k < 16; ++k) {
            float af[8], bf[4];
            *(float4*)&af[0] = *(const float4*)&As[buf][k][ty * 8];
            *(float4*)&af[4] = *(const float4*)&As[buf][k][ty * 8 + 4];
            *(float4*)&bf[0] = *(const float4*)&Bs[buf][k][tx * 4];
#pragma unroll
            for (int i = 0; i < 8; ++i)
#pragma unroll
                for (int j = 0; j < 4; ++j)
                    acc[i][j] = fmaf(af[i], bf[j], acc[i][j]);
        }
    }

    if (MODE == 2) {
        // fused dpfp: this tile is exactly head h = bn/64. Per row: 64 head-cols live
        // on 16 tx-lanes (4 each). Roll needs col-1 (one intra-16-lane shuffle);
        // L1 norm over the 128 outputs via rowsum16 across tx.
        const int h  = bn >> 6;
        const int ln = t & 63;
        const int lnp = (ln & 48) | ((ln + 15) & 15);   // same ty-row, tx-1 (mod 16)
#pragma unroll
        for (int i = 0; i < 8; ++i) {
            const int m = bm + ty * 8 + i;
            float ap[4], an[4];
#pragma unroll
            for (int j = 0; j < 4; ++j) {
                ap[j] = fmaxf(acc[i][j], 0.f);
                an[j] = fmaxf(-acc[i][j], 0.f);
            }
            const float sap = __shfl(ap[3], lnp);
            const float san = __shfl(an[3], lnp);
            const float p0  = (tx == 0) ? san : sap;    // col0 wraps to an[63]
            const float p64 = (tx == 0) ? sap : san;    // col64 wraps to ap[63]
            float y0[4], y1[4];
            y0[0] = ap[0] * p0;    y1[0] = an[0] * p64;
            y0[1] = ap[1] * ap[0]; y1[1] = an[1] * an[0];
            y0[2] = ap[2] * ap[1]; y1[2] = an[2] * an[1];
            y0[3] = ap[3] * ap[2]; y1[3] = an[3] * an[2];
            float s = (y0[0] + y0[1] + y0[2] + y0[3]) + (y1[0] + y1[1] + y1[2] + y1[3]);
            s = rowsum16(s);
            const float inv = 1.f / (s + 1e-6f);
            float4 o0, o1;
            o0.x = y0[0] * inv; o0.y = y0[1] * inv; o0.z = y0[2] * inv; o0.w = y0[3] * inv;
            o1.x = y1[0] * inv; o1.y = y1[1] * inv; o1.z = y1[2] * inv; o1.w = y1[3] * inv;
            *(float4*)(C + (size_t)m * ldc + h * 128 + tx * 4)      = o0;
            *(float4*)(C + (size_t)m * ldc + h * 128 + 64 + tx * 4) = o1;
        }
    } else {
#pragma unroll
        for (int i = 0; i < 8; ++i) {
            const int m = bm + ty * 8 + i;
            float4 o;
            o.x = acc[i][0]; o.y = acc[i][1]; o.z = acc[i][2]; o.w = acc[i][3];
            if (MODE == 1) {
                const float4 bb = *(const float4*)(bias + bn + tx * 4);
                o.x += bb.x; o.y += bb.y; o.z += bb.z; o.w += bb.w;
            }
            *(float4*)(C + (size_t)m * ldc + bn + tx * 4) = o;
        }
    }
}

// ---------------- gate: beta = sigmoid(x @ Wg), [32768, 8], whole sequence ----------------
__global__ __launch_bounds__(256)
void gemm_g_kernel(const float* __restrict__ X, const float* __restrict__ Wg,
                   float* __restrict__ Bt)
{
    const int idx = blockIdx.x * 256 + threadIdx.x;   // 262144 total
    const int row = idx >> 3;
    const int c   = idx & 7;
    const float4* x4 = (const float4*)(X + (size_t)row * DMODEL);
    float acc = 0.f;
    for (int k4 = 0; k4 < 128; ++k4) {
        const float4 xv = x4[k4];
        acc = fmaf(xv.x, Wg[(k4 * 4 + 0) * 8 + c], acc);
        acc = fmaf(xv.y, Wg[(k4 * 4 + 1) * 8 + c], acc);
        acc = fmaf(xv.z, Wg[(k4 * 4 + 2) * 8 + c], acc);
        acc = fmaf(xv.w, Wg[(k4 * 4 + 3) * 8 + c], acc);
    }
    Bt[idx] = 1.f / (1.f + expf(-acc));
}

// ---------------- scan ----------------
// Row-independent delta-rule chains, one CHUNK of steps. Block = (b,h, row-group of 16).
// 256 threads = 16 rows x 16 col-lanes. Thread c owns cols [4c,4c+4) U [64+4c,64+4c+4).
// 2-step look-ahead linearization (R1) kept. R2 change: beta packed into sd.w so the
// per-step DS count drops 7 -> 6 (tests the DS-pipe-throughput theory: 28 DS/step/CU
// x ~16cyc ~= the measured 452 cyc/step). Output now stored TRANSPOSED (outsT[512][8192])
// so the Wo GEMM reads it as a TN operand.
__global__ __launch_bounds__(256)
void scan_kernel(const float* __restrict__ Qp, const float* __restrict__ Kp,
                 const float* __restrict__ Vd, const float* __restrict__ Bt,
                 float* __restrict__ outsT, float* __restrict__ Wst,
                 int s0, int first)
{
    const int blk = blockIdx.x;
    const int bh  = blk & 63;
    const int rg  = blk >> 6;
    const int b   = bh >> 3;
    const int h   = bh & 7;
    const int t   = threadIdx.x;
    const int c      = t & 15;     // col lane
    const int rloc   = t >> 4;     // row within group of 16
    const int wv  = t >> 6;        // wave id 0..3
    const int ln  = t & 63;        // lane within wave

    __shared__ __align__(16) float sk[2][SB][PHI];
    __shared__ __align__(16) float sq[2][SB][PHI];
    __shared__ __align__(16) float sv[2][SB][16];
    __shared__ __align__(16) float sb2[2][SB];
    __shared__ __align__(16) float sd[2][SB][4];   // {kk, kq1, kq0, beta}

    const size_t bh128 = (size_t)(b * 8 + h) * 128;

    float w[8];
    float* wslot = Wst + (size_t)blk * 2048 + t * 8;
    if (first) {
#pragma unroll
        for (int j = 0; j < 8; ++j) w[j] = 0.f;
    } else {
        const float4 w0 = *(const float4*)(wslot);
        const float4 w1 = *(const float4*)(wslot + 4);
        w[0] = w0.x; w[1] = w0.y; w[2] = w0.z; w[3] = w0.w;
        w[4] = w1.x; w[5] = w1.y; w[6] = w1.z; w[7] = w1.w;
    }

    auto stage = [&](int sbuf, int sb) {
        const int sqb = sb * SB;
        if (wv < 2) {
#pragma unroll
            for (int i = 0; i < 8; ++i) {
                const int L  = i * 128 + wv * 64 + ln;
                const int sl = L >> 5, c4 = L & 31;
                async16(Kp + (size_t)(sqb + sl) * 8192 + bh128 + c4 * 4,
                        &sk[sbuf][0][0] + L * 4);
            }
            {
                const int L  = wv * 64 + ln;
                const int sl = L >> 2, c4 = L & 3;
                async16(Vd + (size_t)(sqb + sl) * 4096 + b * 512 + h * 64 + rg * 16 + c4 * 4,
                        &sv[sbuf][0][0] + L * 4);
            }
        } else {
#pragma unroll
            for (int i = 0; i < 8; ++i) {
                const int L  = i * 128 + (wv - 2) * 64 + ln;
                const int sl = L >> 5, c4 = L & 31;
                async16(Qp + (size_t)(sqb + sl) * 8192 + bh128 + c4 * 4,
                        &sq[sbuf][0][0] + L * 4);
            }
            if (wv == 2 && ln < SB) {
                async4(Bt + (size_t)(s0 + sqb + ln) * 64 + b * 8 + h,
                       &sb2[sbuf][0] + ln);
            }
        }
    };

    auto dots_phase = [&](int buf, int sb) {
        const int sl0 = 2 * rloc;
        const float* kmp = (rloc == 0) ? &sk[buf ^ 1][SB - 1][0] : &sk[buf][sl0 - 1][0];
        const float4 km0 = *(const float4*)(kmp + 4 * c);
        const float4 km1 = *(const float4*)(kmp + 64 + 4 * c);
        const float4 ka0 = *(const float4*)&sk[buf][sl0][4 * c];
        const float4 ka1 = *(const float4*)&sk[buf][sl0][64 + 4 * c];
        const float4 kb0 = *(const float4*)&sk[buf][sl0 + 1][4 * c];
        const float4 kb1 = *(const float4*)&sk[buf][sl0 + 1][64 + 4 * c];
        const float4 qa0 = *(const float4*)&sq[buf][sl0][4 * c];
        const float4 qa1 = *(const float4*)&sq[buf][sl0][64 + 4 * c];
        const float4 qb0 = *(const float4*)&sq[buf][sl0 + 1][4 * c];
        const float4 qb1 = *(const float4*)&sq[buf][sl0 + 1][64 + 4 * c];
        const float kk_a  = rowsum16(dot8(km0, km1, ka0, ka1));
        const float kq1_a = rowsum16(dot8(km0, km1, qa0, qa1));
        const float kq0_a = rowsum16(dot8(ka0, ka1, qa0, qa1));
        const float kk_b  = rowsum16(dot8(ka0, ka1, kb0, kb1));
        const float kq1_b = rowsum16(dot8(ka0, ka1, qb0, qb1));
        const float kq0_b = rowsum16(dot8(kb0, kb1, qb0, qb1));
        if (c == 0) {
            const bool z = (sb == 0) && (rloc == 0);   // chunk's step 0: d_prev == 0
            sd[buf][sl0][0] = z ? 0.f : kk_a;
            sd[buf][sl0][1] = z ? 0.f : kq1_a;
            sd[buf][sl0][2] = kq0_a;
            sd[buf][sl0][3] = sb2[buf][sl0];
            sd[buf][sl0 + 1][0] = kk_b;
            sd[buf][sl0 + 1][1] = kq1_b;
            sd[buf][sl0 + 1][2] = kq0_b;
            sd[buf][sl0 + 1][3] = sb2[buf][sl0 + 1];
        }
    };

    struct Frag { float4 k0, k1, q0, q1; float bb, bv, kk, kq1, kq0; };
    Frag r[4];
    float d_prev = 0.f;

    auto preload = [&](Frag& f, int sbuf, int sl) {
        f.k0 = *(const float4*)&sk[sbuf][sl][4 * c];
        f.k1 = *(const float4*)&sk[sbuf][sl][64 + 4 * c];
        f.q0 = *(const float4*)&sq[sbuf][sl][4 * c];
        f.q1 = *(const float4*)&sq[sbuf][sl][64 + 4 * c];
        const float4 dd = *(const float4*)&sd[sbuf][sl][0];
        f.kk = dd.x; f.kq1 = dd.y; f.kq0 = dd.z; f.bb = dd.w;
        f.bv = f.bb * sv[sbuf][sl][rloc];
    };

    auto step_compute = [&](const Frag& f, const Frag& fp, int g) {
        float A0 = w[0] * f.k0.x;
        float A1 = w[4] * f.k1.x;
        A0 = fmaf(w[1], f.k0.y, A0); A1 = fmaf(w[5], f.k1.y, A1);
        A0 = fmaf(w[2], f.k0.z, A0); A1 = fmaf(w[6], f.k1.z, A1);
        A0 = fmaf(w[3], f.k0.w, A0); A1 = fmaf(w[7], f.k1.w, A1);
        float Q0 = w[0] * f.q0.x;
        float Q1 = w[4] * f.q1.x;
        Q0 = fmaf(w[1], f.q0.y, Q0); Q1 = fmaf(w[5], f.q1.y, Q1);
        Q0 = fmaf(w[2], f.q0.z, Q0); Q1 = fmaf(w[6], f.q1.z, Q1);
        Q0 = fmaf(w[3], f.q0.w, Q0); Q1 = fmaf(w[7], f.q1.w, Q1);
        const float Ar  = rowsum16(A0 + A1);
        const float Aqr = rowsum16(Q0 + Q1);
        w[0] = fmaf(d_prev, fp.k0.x, w[0]);
        w[1] = fmaf(d_prev, fp.k0.y, w[1]);
        w[2] = fmaf(d_prev, fp.k0.z, w[2]);
        w[3] = fmaf(d_prev, fp.k0.w, w[3]);
        w[4] = fmaf(d_prev, fp.k1.x, w[4]);
        w[5] = fmaf(d_prev, fp.k1.y, w[5]);
        w[6] = fmaf(d_prev, fp.k1.z, w[6]);
        w[7] = fmaf(d_prev, fp.k1.w, w[7]);
        const float a = fmaf(d_prev, f.kk, Ar);
        const float d = fmaf(-f.bb, a, f.bv);
        float o = fmaf(d_prev, f.kq1, Aqr);
        o = fmaf(d, f.kq0, o);
        if (c == 0)
            outsT[(size_t)(h * DK + rg * 16 + rloc) * CROWS + g * BATCH + b] = o;
        d_prev = d;
    };

    r[3].k0 = make_float4(0.f, 0.f, 0.f, 0.f);
    r[3].k1 = make_float4(0.f, 0.f, 0.f, 0.f);

    stage(0, 0);
    for (int sb = 0; sb < NSB; ++sb) {
        const int buf = sb & 1;
        __syncthreads();                     // staged loads for buf complete
        dots_phase(buf, sb);
        __syncthreads();                     // sd visible; prev-buffer boundary reads done
        if (sb + 1 < NSB) stage(buf ^ 1, sb + 1);
        preload(r[0], buf, 0);
        preload(r[1], buf, 1);
#pragma unroll
        for (int s = 0; s < SB; ++s) {
            if (s + 2 < SB) preload(r[(s + 2) & 3], buf, s + 2);
            step_compute(r[s & 3], r[(s + 3) & 3], sb * SB + s);
        }
    }

    // apply the pending final update (frag 1023 lives in slot 3)
    w[0] = fmaf(d_prev, r[3].k0.x, w[0]);
    w[1] = fmaf(d_prev, r[3].k0.y, w[1]);
    w[2] = fmaf(d_prev, r[3].k0.z, w[2]);
    w[3] = fmaf(d_prev, r[3].k0.w, w[3]);
    w[4] = fmaf(d_prev, r[3].k1.x, w[4]);
    w[5] = fmaf(d_prev, r[3].k1.y, w[5]);
    w[6] = fmaf(d_prev, r[3].k1.z, w[6]);
    w[7] = fmaf(d_prev, r[3].k1.w, w[7]);

    float4 w0, w1;
    w0.x = w[0]; w0.y = w[1]; w0.z = w[2]; w0.w = w[3];
    w1.x = w[4]; w1.y = w[5]; w1.z = w[6]; w1.w = w[7];
    *(float4*)(wslot)     = w0;
    *(float4*)(wslot + 4) = w1;
}

extern "C" void kernel_launch(void* const* d_in, const int* in_sizes, int n_in,
                              void* d_out, int out_size, void* d_ws, size_t ws_size,
                              hipStream_t stream)
{
    const float* x  = (const float*)d_in[0];
    const float* Wq = (const float*)d_in[1];
    const float* Wk = (const float*)d_in[2];
    const float* Wv = (const float*)d_in[3];
    const float* Wg = (const float*)d_in[4];
    const float* Wo = (const float*)d_in[5];
    const float* bo = (const float*)d_in[6];
    float* out = (float*)d_out;

    // workspace (floats), ~104 MB total. XTc (x^T per chunk) ALIASES tmp (scan outsT):
    // per chunk the lifetime is  transpose->XTc | QKV GEMMs read XTc | scan writes tmp |
    // Wo GEMM reads tmp | next chunk's transpose overwrites — stream-ordered, no overlap.
    float* ws  = (float*)d_ws;
    float* XTc = ws;                                   // [512][8192]  (= tmp)
    float* tmp = ws;                                   // [512][8192]  (scan outsT)
    float* Qp  = ws  + (size_t)512 * CROWS;            // [8192][1024]
    float* Kp  = Qp  + (size_t)CROWS * 1024;           // [8192][1024]
    float* Vd  = Kp  + (size_t)CROWS * 1024;           // [8192][512]
    float* Bt  = Vd  + (size_t)CROWS * 512;            // [32768][8]
    float* Wst = Bt  + (size_t)(SEQ * BATCH) * 8;      // [256][2048]
    (void)in_sizes; (void)n_in; (void)out_size; (void)ws_size;

    const dim3 gt(CROWS / 64, DMODEL / 64);  // (128, 8) transpose grid
    const dim3 gg(CROWS / 128, DMODEL / 64); // (64, 8) = 512 workgroups, 2 blocks/CU
    const int NCH = SEQ / CHUNK;             // 4

    gemm_g_kernel<<<(SEQ * BATCH * 8) / 256, 256, 0, stream>>>(x, Wg, Bt);

    for (int c = 0; c < NCH; ++c) {
        const float* xc = x + (size_t)c * CROWS * DMODEL;
        transpose_kernel<<<gt, 256, 0, stream>>>(xc, XTc);
        gemm_tn<2><<<gg, 256, 0, stream>>>(XTc, Wq, nullptr, Qp, CROWS, 1024);
        gemm_tn<2><<<gg, 256, 0, stream>>>(XTc, Wk, nullptr, Kp, CROWS, 1024);
        gemm_tn<0><<<gg, 256, 0, stream>>>(XTc, Wv, nullptr, Vd, CROWS, 512);
        scan_kernel<<<256, 256, 0, stream>>>(Qp, Kp, Vd, Bt, tmp, Wst,
                                             c * CHUNK, c == 0 ? 1 : 0);
        gemm_tn<1><<<gg, 256, 0, stream>>>(tmp, Wo, bo,
                                           out + (size_t)c * CROWS * DMODEL,
                                           CROWS, 512);
    }
}